// Round 18
// baseline (113.710 us; speedup 1.0000x reference)
//
#include <hip/hip_runtime.h>
#include <hip/hip_bf16.h>

typedef unsigned short u16;
typedef __attribute__((ext_vector_type(4))) short short4v;
typedef __attribute__((ext_vector_type(8))) short short8v;
typedef __attribute__((ext_vector_type(4))) float float4v;

#define NF 2
#define NLOC 4096
#define NALL 8192
#define NNEI_ 138
#define X2STR 76   // u16 stride of X2 rows: 152 B -> b64-aligned, ~2-way banks both sides

// Compiler-only ordering fence (strict-aliasing write->read on LDS, same-wave FIFO in HW).
#define COMPILER_LDS_FENCE() asm volatile("" ::: "memory")

__device__ __forceinline__ float fast_tanh(float a) {
#if __has_builtin(__builtin_amdgcn_exp2f) && __has_builtin(__builtin_amdgcn_rcpf)
    float t = __builtin_amdgcn_exp2f(a * 2.885390081777927f);  // exp(2a)
    return 1.0f - 2.0f * __builtin_amdgcn_rcpf(t + 1.0f);
#else
    float t = exp2f(a * 2.885390081777927f);
    return 1.0f - 2.0f / (t + 1.0f);
#endif
}

__device__ __forceinline__ u16 f2bf(float x) {
    __hip_bfloat16 h = __float2bfloat16(x);
    return *reinterpret_cast<u16*>(&h);
}

__device__ __forceinline__ float bf2f(u16 b) {
    union { unsigned int u; float f; } c;
    c.u = ((unsigned int)b) << 16;
    return c.f;
}

// Pack weights into MFMA B-fragment order (bf16), zero-padded.
// B1: [2 types][4 ntiles][64 lanes][8 elems]   (K=25->32, N=50->64)
// B2: [2 types][2 ktiles][7 ntiles][64][8]     (K=50->64, N=100->112)
__global__ void prep_weights(const float* __restrict__ w1, const float* __restrict__ w2,
                             __hip_bfloat16* __restrict__ wsbf) {
    int i = threadIdx.x + blockIdx.x * blockDim.x;
    if (i < 4096) {
        int e = i & 7, lane = (i >> 3) & 63, nt = (i >> 9) & 3, t = i >> 11;
        int k = (lane >> 4) * 8 + e, j = nt * 16 + (lane & 15);
        float v = (k < 25 && j < 50) ? w1[t * 1250 + k * 50 + j] : 0.0f;
        wsbf[i] = __float2bfloat16(v);
    } else if (i < 4096 + 14336) {
        int j2 = i - 4096;
        int e = j2 & 7, lane = (j2 >> 3) & 63;
        int q = j2 >> 9;
        int nt = q % 7, kt = (q / 7) & 1, t = q / 14;
        int k = kt * 32 + (lane >> 4) * 8 + e, j = nt * 16 + (lane & 15);
        float v = (k < 50 && j < 100) ? w2[t * 5000 + k * 100 + j] : 0.0f;
        wsbf[4096 + j2] = __float2bfloat16(v);
    }
}

// WAVE-INDEPENDENT ATOMS: each wave owns one atom end-to-end (4 atoms/block).
// No per-atom barriers, no cross-wave merge; all working LDS is wave-private.
// Rows 0-45 = type0 nbrs 0-45; 46,47 pad; rows 48-139 = type1 nbrs 46-137;
// 140-143 pad. 9 M-tiles of 16 rows per atom; L0 computed JIT per tile.
__global__ __launch_bounds__(256, 3) void descr_mfma(
    const float* __restrict__ coord, const int* __restrict__ atype,
    const int* __restrict__ nlist, const float* __restrict__ mean,
    const float* __restrict__ stddev,
    const float* __restrict__ w0, const float* __restrict__ b0,
    const float* __restrict__ b1, const float* __restrict__ b2,
    const __hip_bfloat16* __restrict__ B1f, const __hip_bfloat16* __restrict__ B2f,
    float* __restrict__ out_res, float* __restrict__ out_sw)
{
    __shared__ __align__(16) u16 B1L[4096];          //  8192 B, B1 pack (both types)
    __shared__ __align__(16) u16 B2L[2 * 7168];      // 28672 B, B2 pack (both types)
    __shared__ __align__(16) u16 Xt[4 * 16 * 32];    //  4096 B, per-wave L0 tile [16][32], swizzled
    __shared__ __align__(16) u16 X2[4 * 16 * X2STR]; //  9728 B, per-wave x2 tile [16][76]
    __shared__ float sL[4][144];                     //  2304 B, per-wave s values
    __shared__ float s2scr[4][64];                   //  1024 B, per-wave s2 exchange

    const int tid = threadIdx.x, wave = tid >> 6, lane = tid & 63;
    const int m = lane & 15, qt = lane >> 4;
    const int b = blockIdx.x * 4 + wave;             // this wave's atom
    const int f = b >> 12, il = b & 4095;

    // ---------------- stage B1+B2 packs into LDS once per block ----------------
    {
        const uint4* s1 = reinterpret_cast<const uint4*>(B1f);   // 512 uint4
        uint4* d1 = reinterpret_cast<uint4*>(B1L);
        d1[tid] = s1[tid];
        d1[tid + 256] = s1[tid + 256];
        const uint4* s2p = reinterpret_cast<const uint4*>(B2f);  // 1792 uint4
        uint4* d2 = reinterpret_cast<uint4*>(B2L);
#pragma unroll
        for (int i = 0; i < 7; ++i) d2[tid + i * 256] = s2p[tid + i * 256];
    }
    __syncthreads();   // the ONLY barrier in the kernel

    // ---------------- per-col constants, BOTH types resident ----------------
    float b1v0[4], b1v1[4], b2v0[7], b2v1[7];
    int rofb[4];   // residual in-row byte offset: (slot<<4)|obyte (pre-swizzle)
#pragma unroll
    for (int nt = 0; nt < 4; ++nt) {
        const int col = nt * 16 + m;
        b1v0[nt] = (col < 50) ? b1[col] : 0.0f;
        b1v1[nt] = (col < 50) ? b1[50 + col] : 0.0f;
        const int cm = (col < 25) ? col : ((col < 50) ? (col - 25) : 0);
        rofb[nt] = ((cm >> 3) << 4) | ((cm & 7) * 2);
    }
#pragma unroll
    for (int nt = 0; nt < 7; ++nt) {
        const int col = nt * 16 + m;
        b2v0[nt] = (col < 100) ? b2[col] : 0.0f;
        b2v1[nt] = (col < 100) ? b2[100 + col] : 0.0f;
    }

    const int aty = atype[f * NALL + il];
    const float cx = coord[(f * NALL + il) * 3 + 0];
    const float cy = coord[(f * NALL + il) * 3 + 1];
    const float cz = coord[(f * NALL + il) * 3 + 2];

    // ---------------- phase S: s for all 144 rows (3 passes, all lanes) ----------------
#pragma unroll
    for (int p = 0; p < 3; ++p) {
        const int row = p * 64 + lane;
        if (row < 144) {
            float s = 0.0f;
            const bool valid = (row < 46) || (row >= 48 && row < 140);
            if (valid) {
                const int n = (row < 46) ? row : (row - 2);   // neighbor 0..137
                const int jn = nlist[b * NNEI_ + n];
                float sw = 0.0f, env = 0.0f;
                if (jn >= 0) {
                    float dx = coord[(f * NALL + jn) * 3 + 0] - cx;
                    float dy = coord[(f * NALL + jn) * 3 + 1] - cy;
                    float dz = coord[(f * NALL + jn) * 3 + 2] - cz;
                    float len = sqrtf(dx * dx + dy * dy + dz * dz);
                    float uu = (len - 0.5f) * (1.0f / 5.5f);
                    float vv = uu * uu * uu * (uu * (-6.0f * uu + 15.0f) - 10.0f) + 1.0f;
                    sw = (len <= 0.5f) ? 1.0f : ((len >= 6.0f) ? 0.0f : vv);
                    env = sw / len;
                }
                out_sw[b * NNEI_ + n] = sw;
                s = (env - mean[aty * NNEI_ + n]) / stddev[aty * NNEI_ + n];
            }
            sL[wave][row] = s;
        }
    }
    COMPILER_LDS_FENCE();

    float psumr[7] = {0, 0, 0, 0, 0, 0, 0};
    float s2r[4] = {0, 0, 0, 0};
    u16* const Xw = Xt + wave * (16 * 32);
    u16* const X2w = X2 + wave * (16 * X2STR);

    const int r_l = lane >> 2;                                  // L0: 4 lanes per row
    const int part = lane & 3;
    const int slotW = part ^ (r_l & 3) ^ ((r_l >> 2) & 3);      // writer swizzle
    const int slotA = qt ^ (m & 3) ^ ((m >> 2) & 3);            // a1 reader swizzle
    const int g16 = qt << 4;                                    // residual swizzle base

    // ---------------- 9 M-tiles, wave-local (no barriers) ----------------
#pragma unroll 1
    for (int rb = 0; rb < 144; rb += 16) {
        const bool t1 = rb >= 48;
        const int vlimit = (rb == 32) ? 14 : ((rb == 128) ? 12 : 16);
        const float* w0t = w0 + (t1 ? 25 : 0);
        const float* b0t = b0 + (t1 ? 25 : 0);

        // ---- L0 JIT: 16 rows x 25 elems over 64 lanes (4 lanes/row, 1 uint4 each)
        {
            const float sr = sL[wave][rb + r_l];
            unsigned int xp[4];
#pragma unroll
            for (int j = 0; j < 4; ++j) {
                const int kk = part * 4 + j;
                float v0 = 0.0f, v1 = 0.0f;
                if (kk < 13) {
                    v0 = fast_tanh(sr * w0t[2 * kk] + b0t[2 * kk]);
                    if (kk < 12) v1 = fast_tanh(sr * w0t[2 * kk + 1] + b0t[2 * kk + 1]);
                }
                xp[j] = (unsigned int)f2bf(v0) | ((unsigned int)f2bf(v1) << 16);
            }
            *reinterpret_cast<uint4*>(reinterpret_cast<char*>(Xw) + r_l * 64 + slotW * 16)
                = make_uint4(xp[0], xp[1], xp[2], xp[3]);
        }
        COMPILER_LDS_FENCE();

        // ---- L1: a1 from Xw, B1 frag from LDS, eager consume
        short8v a1 = *(const short8v*)(reinterpret_cast<const char*>(Xw) + m * 64 + slotA * 16);
        const u16* B1b = B1L + (t1 ? 2048 : 0) + lane * 8;
        const char* Xrb = reinterpret_cast<const char*>(Xw) + (qt * 4) * 64;
#pragma unroll
        for (int nt = 0; nt < 4; ++nt) {
            short8v b1f = *(const short8v*)(B1b + nt * 512);
            float4v C1 = __builtin_amdgcn_mfma_f32_16x16x32_bf16(
                a1, b1f, (float4v){0.f, 0.f, 0.f, 0.f}, 0, 0, 0);
            const int col = nt * 16 + m;
            const float b1s = t1 ? b1v1[nt] : b1v0[nt];
            float vz0 = 0.f, vz1 = 0.f, vz2 = 0.f, vz3 = 0.f;
            if (col < 50) {
                const int off = rofb[nt] ^ g16;
                float x0 = bf2f(*(const u16*)(Xrb +   0 + (off ^  0)));
                float x1 = bf2f(*(const u16*)(Xrb +  64 + (off ^ 16)));
                float x2_ = bf2f(*(const u16*)(Xrb + 128 + (off ^ 32)));
                float x3 = bf2f(*(const u16*)(Xrb + 192 + (off ^ 48)));
                const int lr0 = qt * 4;
                vz0 = (lr0 + 0 < vlimit) ? (fast_tanh(C1[0] + b1s) + x0) : 0.f;
                vz1 = (lr0 + 1 < vlimit) ? (fast_tanh(C1[1] + b1s) + x1) : 0.f;
                vz2 = (lr0 + 2 < vlimit) ? (fast_tanh(C1[2] + b1s) + x2_) : 0.f;
                vz3 = (lr0 + 3 < vlimit) ? (fast_tanh(C1[3] + b1s) + x3) : 0.f;
            }
            s2r[nt] += vz0 + vz1 + vz2 + vz3;
            u16* q = X2w + (qt * 4) * X2STR + col;   // cols >=50 store zeros
            q[0 * X2STR] = f2bf(vz0);
            q[1 * X2STR] = f2bf(vz1);
            q[2 * X2STR] = f2bf(vz2);
            q[3 * X2STR] = f2bf(vz3);
        }
        COMPILER_LDS_FENCE();

        // ---- L2: a2 via 4x ds_read_b64, B2 frags from LDS
        short8v a2[2];
#pragma unroll
        for (int kt = 0; kt < 2; ++kt) {
            const u16* g = X2w + m * X2STR + kt * 32 + qt * 8;
            short4v lo = *(const short4v*)(g);
            short4v hi = *(const short4v*)(g + 4);
            a2[kt] = __builtin_shufflevector(lo, hi, 0, 1, 2, 3, 4, 5, 6, 7);
        }
        const u16* B2b = B2L + (t1 ? 7168 : 0) + lane * 8;
#pragma unroll
        for (int nt = 0; nt < 7; ++nt) {
            short8v bk0 = *(const short8v*)(B2b + (0 * 7 + nt) * 512);
            short8v bk1 = *(const short8v*)(B2b + (1 * 7 + nt) * 512);
            float4v C2 = __builtin_amdgcn_mfma_f32_16x16x32_bf16(
                a2[0], bk0, (float4v){0.f, 0.f, 0.f, 0.f}, 0, 0, 0);
            C2 = __builtin_amdgcn_mfma_f32_16x16x32_bf16(a2[1], bk1, C2, 0, 0, 0);
            const float b2s = t1 ? b2v1[nt] : b2v0[nt];
            const int col = nt * 16 + m;
            const int lr0 = qt * 4;
#pragma unroll
            for (int r = 0; r < 4; ++r) {
                float g2 = fast_tanh(C2[r] + b2s);
                psumr[nt] += (col < 100 && (lr0 + r) < vlimit) ? g2 : 0.f;
            }
        }
    }

    // ---------------- wave-local reduce + write (no barriers) ----------------
#pragma unroll
    for (int nt = 0; nt < 7; ++nt) {
        float v = psumr[nt];
        v += __shfl_xor(v, 16);
        v += __shfl_xor(v, 32);
        psumr[nt] = v;
    }
#pragma unroll
    for (int nt = 0; nt < 4; ++nt) {
        float v = s2r[nt];
        v += __shfl_xor(v, 16);
        v += __shfl_xor(v, 32);
        s2r[nt] = v;
    }
    if (lane < 16) {
#pragma unroll
        for (int nt = 0; nt < 4; ++nt) s2scr[wave][nt * 16 + lane] = s2r[nt];
    }
    COMPILER_LDS_FENCE();
    if (lane < 16) {
#pragma unroll
        for (int nt = 0; nt < 7; ++nt) {
            const int col = nt * 16 + lane;
            if (col < 100) {
                const int cm = (col < 50) ? col : (col - 50);
                out_res[b * 100 + col] = (psumr[nt] + s2scr[wave][cm]) * (0.2f / 138.0f);
            }
        }
    }
}

extern "C" void kernel_launch(void* const* d_in, const int* in_sizes, int n_in,
                              void* d_out, int out_size, void* d_ws, size_t ws_size,
                              hipStream_t stream) {
    const float* coord  = (const float*)d_in[0];
    const int*   atype  = (const int*)d_in[1];
    const int*   nlist  = (const int*)d_in[2];
    const float* mean   = (const float*)d_in[3];
    const float* stddev = (const float*)d_in[4];
    const float* w0 = (const float*)d_in[5];
    const float* b0 = (const float*)d_in[6];
    const float* w1 = (const float*)d_in[7];
    const float* b1 = (const float*)d_in[8];
    const float* w2 = (const float*)d_in[9];
    const float* b2 = (const float*)d_in[10];

    __hip_bfloat16* wsbf = (__hip_bfloat16*)d_ws;
    float* out_res = (float*)d_out;                 // [2][4096][100]
    float* out_sw  = out_res + NF * NLOC * 100;     // [2][4096][138]

    hipLaunchKernelGGL(prep_weights, dim3(72), dim3(256), 0, stream, w1, w2, wsbf);
    hipLaunchKernelGGL(descr_mfma, dim3((NF * NLOC) / 4), dim3(256), 0, stream,
                       coord, atype, nlist, mean, stddev, w0, b0, b1, b2,
                       wsbf /*B1f*/, wsbf + 4096 /*B2f*/, out_res, out_sw);
}

// Round 19
// 109.843 us; speedup vs baseline: 1.0352x; 1.0352x over previous
//
#include <hip/hip_runtime.h>
#include <hip/hip_bf16.h>

#define NF 2
#define NLOC 4096
#define NALL 8192
#define NNEI_ 138
#define KNOTS 2048          // table knots per type; u_k = k/KNOTS, s = A*u/(1-u)
#define TSTR 128            // padded col stride (100 -> 128)
#define ACOEF 4.0f

// Compiler-only ordering fence (same-wave LDS write->read, HW FIFO).
#define COMPILER_LDS_FENCE() asm volatile("" ::: "memory")

__device__ __forceinline__ float fast_tanh(float a) {
#if __has_builtin(__builtin_amdgcn_exp2f) && __has_builtin(__builtin_amdgcn_rcpf)
    float t = __builtin_amdgcn_exp2f(a * 2.885390081777927f);  // exp(2a)
    return 1.0f - 2.0f * __builtin_amdgcn_rcpf(t + 1.0f);
#else
    float t = exp2f(a * 2.885390081777927f);
    return 1.0f - 2.0f / (t + 1.0f);
#endif
}

// ---------------- table build stage 1: x2[2][KNOTS][64] ----------------
// thread = (t,k): layer0 + layer1(+residual), f32 exact (no bf16).
__global__ void build_x2(const float* __restrict__ w0, const float* __restrict__ b0,
                         const float* __restrict__ w1, const float* __restrict__ b1,
                         float* __restrict__ X2T) {
    const int idx = blockIdx.x * 256 + threadIdx.x;   // 0 .. 2*KNOTS-1
    if (idx >= 2 * KNOTS) return;
    const int t = idx >> 11, k = idx & (KNOTS - 1);
    const float u = (float)k * (1.0f / (float)KNOTS);
    const float s = ACOEF * u / (1.0f - u);
    float x[25];
#pragma unroll
    for (int j = 0; j < 25; ++j)
        x[j] = fast_tanh(s * w0[t * 25 + j] + b0[t * 25 + j]);
    float* o = X2T + (size_t)idx * 64;
#pragma unroll 2
    for (int j = 0; j < 50; ++j) {
        float acc = b1[t * 50 + j];
#pragma unroll
        for (int c = 0; c < 25; ++c) acc += x[c] * w1[t * 1250 + c * 50 + j];
        o[j] = fast_tanh(acc) + x[(j < 25) ? j : (j - 25)];
    }
}

// ---------------- table build stage 2: T[2][KNOTS][TSTR] ----------------
// thread = (t,k,col): layer2(+residual folded: G includes concat residual
// via x2 which already holds h1 + x; here col residual = x2[col%50]).
__global__ void build_T(const float* __restrict__ w2, const float* __restrict__ b2,
                        const float* __restrict__ X2T, float* __restrict__ T) {
    const int idx = blockIdx.x * 256 + threadIdx.x;   // 0 .. 2*KNOTS*TSTR-1
    const int col = idx & (TSTR - 1), tk = idx >> 7;
    if (tk >= 2 * KNOTS) return;
    const int t = tk >> 11;
    float v = 0.0f;
    if (col < 100) {
        const float* x2 = X2T + (size_t)tk * 64;
        float acc = b2[t * 100 + col];
#pragma unroll 2
        for (int c = 0; c < 50; ++c) acc += x2[c] * w2[t * 5000 + c * 100 + col];
        const int cm = (col < 50) ? col : (col - 50);
        v = fast_tanh(acc) + x2[cm];          // layer2 residual: + x2[col%50]
    }
    T[(size_t)tk * TSTR + col] = v;
}

// ---------------- main: s + 1-D table interpolation ----------------
// One wave per atom (4 waves/block, fully wave-independent, no barriers).
// Phase S: 138 per-neighbor scalars s (exact math, identical to R16).
// Interp: lane owns 2 output cols (float2); per neighbor 2 coalesced 512B
// row reads (knot i, i+1) + linear interp. Table L2-resident (2 MB).
__global__ void descr_interp(
    const float* __restrict__ coord, const int* __restrict__ atype,
    const int* __restrict__ nlist, const float* __restrict__ mean,
    const float* __restrict__ stddev, const float* __restrict__ T,
    float* __restrict__ out_res, float* __restrict__ out_sw)
{
    __shared__ float sL[4][NNEI_ + 6];
    const int wave = threadIdx.x >> 6, lane = threadIdx.x & 63;
    const int b = blockIdx.x * 4 + wave;
    const int f = b >> 12, il = b & 4095;

    const int aty = atype[f * NALL + il];
    const float cx = coord[(f * NALL + il) * 3 + 0];
    const float cy = coord[(f * NALL + il) * 3 + 1];
    const float cz = coord[(f * NALL + il) * 3 + 2];

    // ---- phase S: s for all 138 neighbor slots (3 passes) ----
#pragma unroll
    for (int p = 0; p < 3; ++p) {
        const int n = p * 64 + lane;
        if (n < NNEI_) {
            const int jn = nlist[b * NNEI_ + n];
            float sw = 0.0f, env = 0.0f;
            if (jn >= 0) {
                float dx = coord[(f * NALL + jn) * 3 + 0] - cx;
                float dy = coord[(f * NALL + jn) * 3 + 1] - cy;
                float dz = coord[(f * NALL + jn) * 3 + 2] - cz;
                float len = sqrtf(dx * dx + dy * dy + dz * dz);
                float uu = (len - 0.5f) * (1.0f / 5.5f);
                float vv = uu * uu * uu * (uu * (-6.0f * uu + 15.0f) - 10.0f) + 1.0f;
                sw = (len <= 0.5f) ? 1.0f : ((len >= 6.0f) ? 0.0f : vv);
                env = sw / len;     // len==0 -> +inf, handled by interp clamp
            }
            out_sw[b * NNEI_ + n] = sw;
            sL[wave][n] = (env - mean[aty * NNEI_ + n]) / stddev[aty * NNEI_ + n];
        }
    }
    COMPILER_LDS_FENCE();

    // ---- interp: 2 cols per lane, 2 accumulator pairs to break FMA chain ----
    float aAx = 0.f, aAy = 0.f, aBx = 0.f, aBy = 0.f;
    const float* Tl = T + 2 * lane;
#pragma unroll 1
    for (int n = 0; n < NNEI_; n += 2) {   // 138 is even
        {
            float s = sL[wave][n];
            s = fminf(fmaxf(s, 0.0f), 1e8f);
            const float u = s / (s + ACOEF);
            const float pp = u * (float)KNOTS;
            int i = (int)pp; i = (i > KNOTS - 2) ? (KNOTS - 2) : i;
            const float fr = pp - (float)i;
            const float* row = Tl + (size_t)(((n < 46) ? 0 : KNOTS) + i) * TSTR;
            const float2 v0 = *(const float2*)(row);
            const float2 v1 = *(const float2*)(row + TSTR);
            aAx += (v1.x - v0.x) * fr + v0.x;
            aAy += (v1.y - v0.y) * fr + v0.y;
        }
        {
            float s = sL[wave][n + 1];
            s = fminf(fmaxf(s, 0.0f), 1e8f);
            const float u = s / (s + ACOEF);
            const float pp = u * (float)KNOTS;
            int i = (int)pp; i = (i > KNOTS - 2) ? (KNOTS - 2) : i;
            const float fr = pp - (float)i;
            const float* row = Tl + (size_t)(((n + 1 < 46) ? 0 : KNOTS) + i) * TSTR;
            const float2 v0 = *(const float2*)(row);
            const float2 v1 = *(const float2*)(row + TSTR);
            aBx += (v1.x - v0.x) * fr + v0.x;
            aBy += (v1.y - v0.y) * fr + v0.y;
        }
    }
    if (lane < 50) {
        float2 o;
        o.x = (aAx + aBx) * (0.2f / 138.0f);
        o.y = (aAy + aBy) * (0.2f / 138.0f);
        *reinterpret_cast<float2*>(out_res + b * 100 + 2 * lane) = o;
    }
}

extern "C" void kernel_launch(void* const* d_in, const int* in_sizes, int n_in,
                              void* d_out, int out_size, void* d_ws, size_t ws_size,
                              hipStream_t stream) {
    const float* coord  = (const float*)d_in[0];
    const int*   atype  = (const int*)d_in[1];
    const int*   nlist  = (const int*)d_in[2];
    const float* mean   = (const float*)d_in[3];
    const float* stddev = (const float*)d_in[4];
    const float* w0 = (const float*)d_in[5];
    const float* b0 = (const float*)d_in[6];
    const float* w1 = (const float*)d_in[7];
    const float* b1 = (const float*)d_in[8];
    const float* w2 = (const float*)d_in[9];
    const float* b2 = (const float*)d_in[10];

    // ws layout: T [2][KNOTS][TSTR] f32 = 2 MB at offset 0;
    //            X2T [2][KNOTS][64] f32 = 1 MB after it.
    float* T   = (float*)d_ws;
    float* X2T = T + (size_t)2 * KNOTS * TSTR;
    float* out_res = (float*)d_out;                 // [2][4096][100]
    float* out_sw  = out_res + NF * NLOC * 100;     // [2][4096][138]

    hipLaunchKernelGGL(build_x2, dim3((2 * KNOTS + 255) / 256), dim3(256), 0, stream,
                       w0, b0, w1, b1, X2T);
    hipLaunchKernelGGL(build_T, dim3((2 * KNOTS * TSTR + 255) / 256), dim3(256), 0, stream,
                       w2, b2, X2T, T);
    hipLaunchKernelGGL(descr_interp, dim3((NF * NLOC) / 4), dim3(256), 0, stream,
                       coord, atype, nlist, mean, stddev, T, out_res, out_sw);
}

// Round 20
// 76.812 us; speedup vs baseline: 1.4804x; 1.4300x over previous
//
#include <hip/hip_runtime.h>
#include <hip/hip_bf16.h>
#include <hip/hip_fp16.h>

typedef unsigned short u16;
typedef __attribute__((ext_vector_type(4))) short short4v;

#define NF 2
#define NLOC 4096
#define NALL 8192
#define NNEI_ 138
#define KNOTS 1024          // knots per type; u_k = k/KNOTS, s = A*u/(1-u)
#define ROWH 256            // halves per table row (200 used, pad 0) = 512 B
#define ACOEF 4.0f

// Compiler-only ordering fence (same-wave LDS write->read, HW FIFO).
#define COMPILER_LDS_FENCE() asm volatile("" ::: "memory")

__device__ __forceinline__ float fast_tanh(float a) {
#if __has_builtin(__builtin_amdgcn_exp2f) && __has_builtin(__builtin_amdgcn_rcpf)
    float t = __builtin_amdgcn_exp2f(a * 2.885390081777927f);  // exp(2a)
    return 1.0f - 2.0f * __builtin_amdgcn_rcpf(t + 1.0f);
#else
    float t = exp2f(a * 2.885390081777927f);
    return 1.0f - 2.0f / (t + 1.0f);
#endif
}

__device__ __forceinline__ float h2f(short hs) {
    __half h = *reinterpret_cast<__half*>(&hs);
    return __half2float(h);
}

// ---------------- table build stage 1: x2[2][KNOTS][64] f32 ----------------
// thread = (t,k): layer0 + layer1(+concat residual), f32 exact.
// Weight addresses are wave-uniform (t block-uniform) -> s_loads.
__global__ void build_x2(const float* __restrict__ w0, const float* __restrict__ b0,
                         const float* __restrict__ w1, const float* __restrict__ b1,
                         float* __restrict__ X2T) {
    const int idx = blockIdx.x * 256 + threadIdx.x;   // 0 .. 2*KNOTS-1
    if (idx >= 2 * KNOTS) return;
    const int t = idx >> 10, k = idx & (KNOTS - 1);
    const float u = (float)k * (1.0f / (float)KNOTS);
    const float s = ACOEF * u / (1.0f - u);
    float x[25];
#pragma unroll
    for (int j = 0; j < 25; ++j)
        x[j] = fast_tanh(s * w0[t * 25 + j] + b0[t * 25 + j]);
    float* o = X2T + (size_t)idx * 64;
#pragma unroll 2
    for (int j = 0; j < 50; ++j) {
        float acc = b1[t * 50 + j];
#pragma unroll
        for (int c = 0; c < 25; ++c) acc += x[c] * w1[t * 1250 + c * 50 + j];
        o[j] = fast_tanh(acc) + x[(j < 25) ? j : (j - 25)];
    }
}

// ---------------- table build stage 2: TP[2][KNOTS][ROWH] f16, pair-interleaved ----
// Row k layout (halves): idx 4l+0 = G[k][2l], 4l+1 = G[k][2l+1],
//                        idx 4l+2 = G[k+1][2l], 4l+3 = G[k+1][2l+1].
// Each thread computes G[t][k][c] and stores it into row k (as "k" member)
// and row k-1 (as "k+1" member). Pad halves pre-zeroed by hipMemsetAsync.
__global__ void build_T(const float* __restrict__ w2, const float* __restrict__ b2,
                        const float* __restrict__ X2T, u16* __restrict__ TP) {
    const int idx = blockIdx.x * 256 + threadIdx.x;   // (tk, c) over 2*KNOTS*128
    const int c = idx & 127;
    const int tk = idx >> 7;
    if (tk >= 2 * KNOTS || c >= 100) return;
    const int t = tk >> 10, k = tk & (KNOTS - 1);
    const float* x2 = X2T + (size_t)tk * 64;
    float acc = b2[t * 100 + c];
#pragma unroll 2
    for (int cc = 0; cc < 50; ++cc) acc += x2[cc] * w2[t * 5000 + cc * 100 + c];
    const float v = fast_tanh(acc) + x2[(c < 50) ? c : (c - 50)];
    const __half h = __float2half(v);
    const u16 hb = *reinterpret_cast<const u16*>(&h);
    const size_t row = (size_t)(t * KNOTS + k) * ROWH;
    const int l4 = 4 * (c >> 1) + (c & 1);
    TP[row + l4] = hb;                       // "k" member of row k
    if (k > 0) TP[row - ROWH + l4 + 2] = hb; // "k+1" member of row k-1
}

// ---------------- main: s -> (offset, frac) -> f16 table interp ----------------
// One wave per atom (4/block, wave-independent, no barriers).
// Phase S (3 passes, lanes parallel): exact s math + index precompute -> LDS.
// Interp loop: uniform ds_read_b64 + readfirstlane SGPR base + one dwordx2
// per lane per neighbor (512 B/row, both knots & both cols) + 4 cvt + 4 FMA.
__global__ __launch_bounds__(256) void descr_interp(
    const float* __restrict__ coord, const int* __restrict__ atype,
    const int* __restrict__ nlist, const float* __restrict__ mean,
    const float* __restrict__ stddev, const u16* __restrict__ TP,
    float* __restrict__ out_res, float* __restrict__ out_sw)
{
    __shared__ int2 sIF[4][NNEI_ + 2];
    const int wave = threadIdx.x >> 6, lane = threadIdx.x & 63;
    const int b = blockIdx.x * 4 + wave;
    const int f = b >> 12, il = b & 4095;

    const int aty = atype[f * NALL + il];
    const float cx = coord[(f * NALL + il) * 3 + 0];
    const float cy = coord[(f * NALL + il) * 3 + 1];
    const float cz = coord[(f * NALL + il) * 3 + 2];

    // ---- phase S: s, sw, and (row byte offset, frac) for all 138 slots ----
#pragma unroll
    for (int p = 0; p < 3; ++p) {
        const int n = p * 64 + lane;
        if (n < NNEI_) {
            const int jn = nlist[b * NNEI_ + n];
            float sw = 0.0f, env = 0.0f;
            if (jn >= 0) {
                float dx = coord[(f * NALL + jn) * 3 + 0] - cx;
                float dy = coord[(f * NALL + jn) * 3 + 1] - cy;
                float dz = coord[(f * NALL + jn) * 3 + 2] - cz;
                float len = sqrtf(dx * dx + dy * dy + dz * dz);
                float uu = (len - 0.5f) * (1.0f / 5.5f);
                float vv = uu * uu * uu * (uu * (-6.0f * uu + 15.0f) - 10.0f) + 1.0f;
                sw = (len <= 0.5f) ? 1.0f : ((len >= 6.0f) ? 0.0f : vv);
                env = sw / len;          // len==0 -> +inf (self-neighbor)
            }
            out_sw[b * NNEI_ + n] = sw;
            float s = (env - mean[aty * NNEI_ + n]) / stddev[aty * NNEI_ + n];
            s = fminf(fmaxf(s, 0.0f), 1e7f);   // inf clamp: table saturated there
            const float u = s / (s + ACOEF);
            const float pp = u * (float)KNOTS;
            int i = (int)pp;
            i = (i > KNOTS - 2) ? (KNOTS - 2) : i;
            const float fr = pp - (float)i;
            const int off = (((n >= 46) ? KNOTS : 0) + i) * (ROWH * 2); // bytes
            sIF[wave][n] = make_int2(off, __float_as_int(fr));
        }
    }
    COMPILER_LDS_FENCE();

    // ---- interp: lane owns cols (2l, 2l+1); 2-deep unroll, split accumulators ----
    float aAx = 0.f, aAy = 0.f, aBx = 0.f, aBy = 0.f;
    const char* const Tb = (const char*)TP;
    const int loff = lane * 8;
#pragma unroll 1
    for (int n = 0; n < NNEI_; n += 2) {   // 138 is even
        const int2 pA = sIF[wave][n];
        const int2 pB = sIF[wave][n + 1];
        const unsigned soA = (unsigned)__builtin_amdgcn_readfirstlane(pA.x);
        const unsigned soB = (unsigned)__builtin_amdgcn_readfirstlane(pB.x);
        const float frA = __int_as_float(pA.y);
        const float frB = __int_as_float(pB.y);
        const short4v vA = *(const short4v*)(Tb + soA + loff);
        const short4v vB = *(const short4v*)(Tb + soB + loff);
        {
            const float A = h2f(vA[0]), B = h2f(vA[1]), C = h2f(vA[2]), D = h2f(vA[3]);
            aAx += fmaf(frA, C - A, A);
            aAy += fmaf(frA, D - B, B);
        }
        {
            const float A = h2f(vB[0]), B = h2f(vB[1]), C = h2f(vB[2]), D = h2f(vB[3]);
            aBx += fmaf(frB, C - A, A);
            aBy += fmaf(frB, D - B, B);
        }
    }
    if (lane < 50) {
        float2 o;
        o.x = (aAx + aBx) * (0.2f / 138.0f);
        o.y = (aAy + aBy) * (0.2f / 138.0f);
        *reinterpret_cast<float2*>(out_res + b * 100 + 2 * lane) = o;
    }
}

extern "C" void kernel_launch(void* const* d_in, const int* in_sizes, int n_in,
                              void* d_out, int out_size, void* d_ws, size_t ws_size,
                              hipStream_t stream) {
    const float* coord  = (const float*)d_in[0];
    const int*   atype  = (const int*)d_in[1];
    const int*   nlist  = (const int*)d_in[2];
    const float* mean   = (const float*)d_in[3];
    const float* stddev = (const float*)d_in[4];
    const float* w0 = (const float*)d_in[5];
    const float* b0 = (const float*)d_in[6];
    const float* w1 = (const float*)d_in[7];
    const float* b1 = (const float*)d_in[8];
    const float* w2 = (const float*)d_in[9];
    const float* b2 = (const float*)d_in[10];

    // ws: TP f16 pair table [2][KNOTS][ROWH] = 1 MB at 0; X2T f32 [2][KNOTS][64] after.
    u16*   TP  = (u16*)d_ws;
    float* X2T = (float*)((char*)d_ws + (size_t)2 * KNOTS * ROWH * 2);
    float* out_res = (float*)d_out;                 // [2][4096][100]
    float* out_sw  = out_res + NF * NLOC * 100;     // [2][4096][138]

    hipMemsetAsync(TP, 0, (size_t)2 * KNOTS * ROWH * 2, stream);  // zero pad halves
    hipLaunchKernelGGL(build_x2, dim3((2 * KNOTS + 255) / 256), dim3(256), 0, stream,
                       w0, b0, w1, b1, X2T);
    hipLaunchKernelGGL(build_T, dim3((2 * KNOTS * 128) / 256), dim3(256), 0, stream,
                       w2, b2, X2T, TP);
    hipLaunchKernelGGL(descr_interp, dim3((NF * NLOC) / 4), dim3(256), 0, stream,
                       coord, atype, nlist, mean, stddev, TP, out_res, out_sw);
}

// Round 21
// 48.309 us; speedup vs baseline: 2.3538x; 1.5900x over previous
//
#include <hip/hip_runtime.h>
#include <hip/hip_bf16.h>
#include <hip/hip_fp16.h>

typedef unsigned short u16;
typedef __attribute__((ext_vector_type(4))) short short4v;

#define NF 2
#define NLOC 4096
#define NALL 8192
#define NNEI_ 138
#define KNOTS 1024          // knots per type; u_k = k/KNOTS, s = A*u/(1-u)
#define ROWH 256            // halves per table row (200 used + pad) = 512 B
#define ACOEF 4.0f

// Compiler-only ordering fence (same-wave LDS write->read, HW FIFO).
#define COMPILER_LDS_FENCE() asm volatile("" ::: "memory")

__device__ __forceinline__ float fast_tanh(float a) {
#if __has_builtin(__builtin_amdgcn_exp2f) && __has_builtin(__builtin_amdgcn_rcpf)
    float t = __builtin_amdgcn_exp2f(a * 2.885390081777927f);  // exp(2a)
    return 1.0f - 2.0f * __builtin_amdgcn_rcpf(t + 1.0f);
#else
    float t = exp2f(a * 2.885390081777927f);
    return 1.0f - 2.0f / (t + 1.0f);
#endif
}

// ---------------- fused table build: one dispatch, no workspace staging ----
// Block = 256 threads = 2 groups of 128; group g owns tk = blockIdx.x*2+g.
// Stage x[25] -> x2[50] in LDS (block barriers), then thread c computes
// T[t][k][c] (c<100) or pad zero (c in [100,128)), storing the knot-pair-
// interleaved f16 layout:
//   row k halves: 4l+0 = G[k][2l], 4l+1 = G[k][2l+1],
//                 4l+2 = G[k+1][2l], 4l+3 = G[k+1][2l+1]
// Thread (k,c) writes row k's "k" slot and row k-1's "k+1" slot: all writes
// are address-disjoint across the grid -> race-free without ordering.
__global__ __launch_bounds__(256) void build_table(
    const float* __restrict__ w0, const float* __restrict__ b0,
    const float* __restrict__ w1, const float* __restrict__ b1,
    const float* __restrict__ w2, const float* __restrict__ b2,
    u16* __restrict__ TP)
{
    __shared__ float xs[2][25];
    __shared__ float x2s[2][50];
    const int g = threadIdx.x >> 7, lt = threadIdx.x & 127;
    const int tk = blockIdx.x * 2 + g;              // 0 .. 2*KNOTS-1
    const int t = tk >> 10, k = tk & (KNOTS - 1);
    const float u = (float)k * (1.0f / (float)KNOTS);
    const float s = ACOEF * u / (1.0f - u);

    if (lt < 25)
        xs[g][lt] = fast_tanh(s * w0[t * 25 + lt] + b0[t * 25 + lt]);
    __syncthreads();
    if (lt < 50) {
        float acc = b1[t * 50 + lt];
#pragma unroll
        for (int c = 0; c < 25; ++c) acc += xs[g][c] * w1[t * 1250 + c * 50 + lt];
        x2s[g][lt] = fast_tanh(acc) + xs[g][(lt < 25) ? lt : (lt - 25)];
    }
    __syncthreads();

    const int c = lt;
    const size_t row = (size_t)tk * ROWH;
    const int l4 = 4 * (c >> 1) + (c & 1);
    u16 hb = 0;
    if (c < 100) {
        float acc = b2[t * 100 + c];
#pragma unroll 2
        for (int cc = 0; cc < 50; ++cc) acc += x2s[g][cc] * w2[t * 5000 + cc * 100 + c];
        const float v = fast_tanh(acc) + x2s[g][(c < 50) ? c : (c - 50)];
        const __half h = __float2half(v);
        hb = *reinterpret_cast<const u16*>(&h);
    }
    TP[row + l4] = hb;                        // "k" member of row k (or pad 0)
    if (k > 0) TP[row - ROWH + l4 + 2] = hb;  // "k+1" member of row k-1
}

// ---------------- main: s -> (offset, frac) -> packed f16 interp ----------
// One wave per atom (4/block, wave-independent, no barriers).
// Phase S (3 passes, lanes parallel): exact s math + index precompute -> LDS.
// Interp loop: unroll-4 (4 table loads in flight; loop is L2-latency-bound),
// uniform ds_read + readfirstlane SGPR base + 1 dwordx2/lane/neighbor,
// packed __half2 lerp (v_pk_sub/v_pk_fma) + f32 accumulation.
__global__ __launch_bounds__(256) void descr_interp(
    const float* __restrict__ coord, const int* __restrict__ atype,
    const int* __restrict__ nlist, const float* __restrict__ mean,
    const float* __restrict__ stddev, const u16* __restrict__ TP,
    float* __restrict__ out_res, float* __restrict__ out_sw)
{
    __shared__ int2 sIF[4][NNEI_ + 2];
    const int wave = threadIdx.x >> 6, lane = threadIdx.x & 63;
    const int b = blockIdx.x * 4 + wave;
    const int f = b >> 12, il = b & 4095;

    const int aty = atype[f * NALL + il];
    const float cx = coord[(f * NALL + il) * 3 + 0];
    const float cy = coord[(f * NALL + il) * 3 + 1];
    const float cz = coord[(f * NALL + il) * 3 + 2];

    // ---- phase S: s, sw, and (row byte offset, frac) for all 138 slots ----
#pragma unroll
    for (int p = 0; p < 3; ++p) {
        const int n = p * 64 + lane;
        if (n < NNEI_) {
            const int jn = nlist[b * NNEI_ + n];
            float sw = 0.0f, env = 0.0f;
            if (jn >= 0) {
                float dx = coord[(f * NALL + jn) * 3 + 0] - cx;
                float dy = coord[(f * NALL + jn) * 3 + 1] - cy;
                float dz = coord[(f * NALL + jn) * 3 + 2] - cz;
                float len = sqrtf(dx * dx + dy * dy + dz * dz);
                float uu = (len - 0.5f) * (1.0f / 5.5f);
                float vv = uu * uu * uu * (uu * (-6.0f * uu + 15.0f) - 10.0f) + 1.0f;
                sw = (len <= 0.5f) ? 1.0f : ((len >= 6.0f) ? 0.0f : vv);
                env = sw / len;          // len==0 -> +inf (self-neighbor)
            }
            out_sw[b * NNEI_ + n] = sw;
            float s = (env - mean[aty * NNEI_ + n]) / stddev[aty * NNEI_ + n];
            s = fminf(fmaxf(s, 0.0f), 1e7f);   // inf clamp: table saturated there
            const float u = s / (s + ACOEF);
            const float pp = u * (float)KNOTS;
            int i = (int)pp;
            i = (i > KNOTS - 2) ? (KNOTS - 2) : i;
            const float fr = pp - (float)i;
            const int off = (((n >= 46) ? KNOTS : 0) + i) * (ROWH * 2); // bytes
            sIF[wave][n] = make_int2(off, __float_as_int(fr));
        }
    }
    COMPILER_LDS_FENCE();

    // ---- interp: lane owns cols (2l, 2l+1); unroll 4, 4 accumulator pairs ----
    float2 a0 = {0.f, 0.f}, a1v = {0.f, 0.f}, a2v = {0.f, 0.f}, a3v = {0.f, 0.f};
    const char* const Tb = (const char*)TP;
    const int loff = lane * 8;

    auto lerp_acc = [&](short4v v, float fr, float2& acc) {
        union { short4v s4; __half2 h2[2]; } cv; cv.s4 = v;
        const __half2 d = __hsub2(cv.h2[1], cv.h2[0]);
        const __half2 r = __hfma2(__float2half2_rn(fr), d, cv.h2[0]);
        acc.x += __low2float(r);
        acc.y += __high2float(r);
    };

#pragma unroll 1
    for (int n = 0; n < 136; n += 4) {   // 138 = 4*34 + 2
        const int2 p0 = sIF[wave][n];
        const int2 p1 = sIF[wave][n + 1];
        const int2 p2 = sIF[wave][n + 2];
        const int2 p3 = sIF[wave][n + 3];
        const unsigned s0 = (unsigned)__builtin_amdgcn_readfirstlane(p0.x);
        const unsigned s1 = (unsigned)__builtin_amdgcn_readfirstlane(p1.x);
        const unsigned s2 = (unsigned)__builtin_amdgcn_readfirstlane(p2.x);
        const unsigned s3 = (unsigned)__builtin_amdgcn_readfirstlane(p3.x);
        const short4v v0 = *(const short4v*)(Tb + s0 + loff);
        const short4v v1 = *(const short4v*)(Tb + s1 + loff);
        const short4v v2 = *(const short4v*)(Tb + s2 + loff);
        const short4v v3 = *(const short4v*)(Tb + s3 + loff);
        lerp_acc(v0, __int_as_float(p0.y), a0);
        lerp_acc(v1, __int_as_float(p1.y), a1v);
        lerp_acc(v2, __int_as_float(p2.y), a2v);
        lerp_acc(v3, __int_as_float(p3.y), a3v);
    }
    {   // tail: n = 136, 137
        const int2 p0 = sIF[wave][136];
        const int2 p1 = sIF[wave][137];
        const unsigned s0 = (unsigned)__builtin_amdgcn_readfirstlane(p0.x);
        const unsigned s1 = (unsigned)__builtin_amdgcn_readfirstlane(p1.x);
        const short4v v0 = *(const short4v*)(Tb + s0 + loff);
        const short4v v1 = *(const short4v*)(Tb + s1 + loff);
        lerp_acc(v0, __int_as_float(p0.y), a0);
        lerp_acc(v1, __int_as_float(p1.y), a1v);
    }

    if (lane < 50) {
        float2 o;
        o.x = (a0.x + a1v.x + a2v.x + a3v.x) * (0.2f / 138.0f);
        o.y = (a0.y + a1v.y + a2v.y + a3v.y) * (0.2f / 138.0f);
        *reinterpret_cast<float2*>(out_res + b * 100 + 2 * lane) = o;
    }
}

extern "C" void kernel_launch(void* const* d_in, const int* in_sizes, int n_in,
                              void* d_out, int out_size, void* d_ws, size_t ws_size,
                              hipStream_t stream) {
    const float* coord  = (const float*)d_in[0];
    const int*   atype  = (const int*)d_in[1];
    const int*   nlist  = (const int*)d_in[2];
    const float* mean   = (const float*)d_in[3];
    const float* stddev = (const float*)d_in[4];
    const float* w0 = (const float*)d_in[5];
    const float* b0 = (const float*)d_in[6];
    const float* w1 = (const float*)d_in[7];
    const float* b1 = (const float*)d_in[8];
    const float* w2 = (const float*)d_in[9];
    const float* b2 = (const float*)d_in[10];

    u16* TP = (u16*)d_ws;                           // [2][KNOTS][ROWH] f16 = 1 MB
    float* out_res = (float*)d_out;                 // [2][4096][100]
    float* out_sw  = out_res + NF * NLOC * 100;     // [2][4096][138]

    hipLaunchKernelGGL(build_table, dim3(KNOTS), dim3(256), 0, stream,
                       w0, b0, w1, b1, w2, b2, TP);
    hipLaunchKernelGGL(descr_interp, dim3((NF * NLOC) / 4), dim3(256), 0, stream,
                       coord, atype, nlist, mean, stddev, TP, out_res, out_sw);
}